// Round 13
// baseline (435.066 us; speedup 1.0000x reference)
//
#include <hip/hip_runtime.h>

#define BB 32
#define TT 128
#define II 256
#define HH 256
#define OO 128
#define FWID 512  // H + I

// d_ws: u64 slots[2][BB][HH] (parity, batch, row) = 128 KB.
// Slot = (stamp<<32)|float_bits(h); step s consumes stamp>=s from parity s&1,
// publishes stamp s+1 into parity (s+1)&1. Agent-scope relaxed (no fences);
// protocol proven on HW in R2/R3/R5/R8/R12.
// Overwrite safety: producer writes stamp s+2 (same parity slot as stamp s)
// only in step s+1, gated on its block's gather(s+1) = all 256 rows at stamp
// s+1 = every block of this batch exited its stamp-s gather check (all
// stamp-s reads complete). The stamp check gates the ds_write exactly as in
// R12 regardless of when the poll loads were ISSUED, so hoisting them does
// not touch the proof. u64 atomics cannot tear.
//
// R13 vs R12 (209 us): software-pipeline the gatherer's poll. R12 issued the
// 4 LLC slot loads only after Phase P completed, exposing the ~700 cy read
// round-trip on the critical cycle. R13 issues them right after Phase P's FMA
// accumulation block; the shuffle-reduce + invn + F-decay + gamma*x tail
// (~500-700 cy) covers the latency, and the post-P check usually passes on
// the first try (stamps landed during P). Stale fallback loop = R12 behavior.

typedef unsigned long long u64;

__device__ __forceinline__ u64 slot_ld(const u64* p) {
    return __hip_atomic_load(p, __ATOMIC_RELAXED, __HIP_MEMORY_SCOPE_AGENT);
}

// Full gather (poll loop + LDS stage + flag) -- used for the epilogue where
// latency does not matter.
__device__ __forceinline__ void gather_to_lds(const u64* base, int lane, unsigned us,
                                              float* dst, int* flag, int fval) {
    const u64* p = base + 4 * lane;
    u64 a, b, c, d;
    for (;;) {
        a = slot_ld(p);
        b = slot_ld(p + 1);
        c = slot_ld(p + 2);
        d = slot_ld(p + 3);
        bool ok = ((unsigned)(a >> 32) >= us) & ((unsigned)(b >> 32) >= us) &
                  ((unsigned)(c >> 32) >= us) & ((unsigned)(d >> 32) >= us);
        if (__all(ok)) break;
    }
    float4 hv;
    hv.x = __uint_as_float((unsigned)a);
    hv.y = __uint_as_float((unsigned)b);
    hv.z = __uint_as_float((unsigned)c);
    hv.w = __uint_as_float((unsigned)d);
    *reinterpret_cast<float4*>(dst + 4 * lane) = hv;
    if (lane == 0)
        __hip_atomic_store(flag, fval, __ATOMIC_RELEASE, __HIP_MEMORY_SCOPE_WORKGROUP);
}

__global__ __launch_bounds__(512, 2)
void stpn_kernel(const float* __restrict__ x,      // (B,T,I)
                 const float* __restrict__ wlam,   // (H,FWID)
                 const float* __restrict__ wgam,   // (H,FWID)
                 const float* __restrict__ w,      // (H,FWID)
                 const float* __restrict__ bias,   // (H)
                 const float* __restrict__ wout,   // (O,H)
                 const float* __restrict__ bout,   // (O)
                 float* __restrict__ out,          // tag(4096) | h_T(8192) | F_T
                 u64* __restrict__ slots)
{
    __shared__ __align__(16) float lh[2][HH];      // [parity][row]
    __shared__ int lflag[2];                       // [parity]

    const int tid  = threadIdx.x;
    const int bk   = blockIdx.x;
    const int b    = bk & 31;        // batch
    const int sl   = bk >> 5;        // row slice 0..7 (32 rows each)
    const int wv   = tid >> 6;       // 0..7
    const int lane = tid & 63;
    const int g    = tid >> 4;       // 16-lane group == row-within-slice
    const int i    = tid & 15;       // lane within group
    const int r    = sl * 32 + (g & 31);

    if (tid < 2) lflag[tid] = 0;

    // Per-lane f-chunks of row r: f = 64*k + 4*i + c, k=0..7 (k<4 x-part, k>=4 h-part)
    float4 W4[8], L4[8], G4[8], F4[8];
    {
        const float4* wr = reinterpret_cast<const float4*>(w    + (size_t)r * FWID);
        const float4* lr = reinterpret_cast<const float4*>(wlam + (size_t)r * FWID);
        const float4* gr = reinterpret_cast<const float4*>(wgam + (size_t)r * FWID);
#pragma unroll
        for (int k = 0; k < 8; ++k) {
            W4[k] = wr[k * 16 + i];
            L4[k] = lr[k * 16 + i];
            G4[k] = gr[k * 16 + i];
            F4[k] = make_float4(0.f, 0.f, 0.f, 0.f);
        }
    }
    const float bj = bias[r];
    float hl = 0.f;

    __syncthreads();   // lflag init visible

    for (int s = 0; s < TT; ++s) {
        const int par = s & 1;

        // x load (L2-resident after first pass)
        const float4* xb = reinterpret_cast<const float4*>(x + ((size_t)b * TT + s) * II);
        float4 T0 = xb[i], T1 = xb[16 + i], T2 = xb[32 + i], T3 = xb[48 + i];

        // ---- Phase P part 1: FMA accumulation (independent of h(s)) ----
        float4 tw[4];                      // h-part tw, kept for dot_h
        float4 dx4 = make_float4(0,0,0,0), nv4 = make_float4(0,0,0,0);
        {
            float4 t;
            t.x = W4[0].x + F4[0].x; t.y = W4[0].y + F4[0].y; t.z = W4[0].z + F4[0].z; t.w = W4[0].w + F4[0].w;
            dx4.x = fmaf(T0.x, t.x, dx4.x); dx4.y = fmaf(T0.y, t.y, dx4.y);
            dx4.z = fmaf(T0.z, t.z, dx4.z); dx4.w = fmaf(T0.w, t.w, dx4.w);
            nv4.x = fmaf(t.x, t.x, nv4.x); nv4.y = fmaf(t.y, t.y, nv4.y);
            nv4.z = fmaf(t.z, t.z, nv4.z); nv4.w = fmaf(t.w, t.w, nv4.w);
            t.x = W4[1].x + F4[1].x; t.y = W4[1].y + F4[1].y; t.z = W4[1].z + F4[1].z; t.w = W4[1].w + F4[1].w;
            dx4.x = fmaf(T1.x, t.x, dx4.x); dx4.y = fmaf(T1.y, t.y, dx4.y);
            dx4.z = fmaf(T1.z, t.z, dx4.z); dx4.w = fmaf(T1.w, t.w, dx4.w);
            nv4.x = fmaf(t.x, t.x, nv4.x); nv4.y = fmaf(t.y, t.y, nv4.y);
            nv4.z = fmaf(t.z, t.z, nv4.z); nv4.w = fmaf(t.w, t.w, nv4.w);
            t.x = W4[2].x + F4[2].x; t.y = W4[2].y + F4[2].y; t.z = W4[2].z + F4[2].z; t.w = W4[2].w + F4[2].w;
            dx4.x = fmaf(T2.x, t.x, dx4.x); dx4.y = fmaf(T2.y, t.y, dx4.y);
            dx4.z = fmaf(T2.z, t.z, dx4.z); dx4.w = fmaf(T2.w, t.w, dx4.w);
            nv4.x = fmaf(t.x, t.x, nv4.x); nv4.y = fmaf(t.y, t.y, nv4.y);
            nv4.z = fmaf(t.z, t.z, nv4.z); nv4.w = fmaf(t.w, t.w, nv4.w);
            t.x = W4[3].x + F4[3].x; t.y = W4[3].y + F4[3].y; t.z = W4[3].z + F4[3].z; t.w = W4[3].w + F4[3].w;
            dx4.x = fmaf(T3.x, t.x, dx4.x); dx4.y = fmaf(T3.y, t.y, dx4.y);
            dx4.z = fmaf(T3.z, t.z, dx4.z); dx4.w = fmaf(T3.w, t.w, dx4.w);
            nv4.x = fmaf(t.x, t.x, nv4.x); nv4.y = fmaf(t.y, t.y, nv4.y);
            nv4.z = fmaf(t.z, t.z, nv4.z); nv4.w = fmaf(t.w, t.w, nv4.w);
#pragma unroll
            for (int k = 0; k < 4; ++k) {
                tw[k].x = W4[k + 4].x + F4[k + 4].x; tw[k].y = W4[k + 4].y + F4[k + 4].y;
                tw[k].z = W4[k + 4].z + F4[k + 4].z; tw[k].w = W4[k + 4].w + F4[k + 4].w;
                nv4.x = fmaf(tw[k].x, tw[k].x, nv4.x); nv4.y = fmaf(tw[k].y, tw[k].y, nv4.y);
                nv4.z = fmaf(tw[k].z, tw[k].z, nv4.z); nv4.w = fmaf(tw[k].w, tw[k].w, nv4.w);
            }
        }

        // ---- early poll ISSUE (gatherer wave): LLC round-trip overlaps the
        //      reduce + invn + decay + gamma*x tail below ----
        u64 sa = 0, sb = 0, sc = 0, sd = 0;
        const u64* gp = slots + ((size_t)par * BB + b) * HH + 4 * lane;
        if (wv == 0) {
            sa = slot_ld(gp);
            sb = slot_ld(gp + 1);
            sc = slot_ld(gp + 2);
            sd = slot_ld(gp + 3);
        }

        float dxs = (dx4.x + dx4.y) + (dx4.z + dx4.w);
        float nrm = (nv4.x + nv4.y) + (nv4.z + nv4.w);
#pragma unroll
        for (int off = 1; off <= 8; off <<= 1) {   // 4-level reduce over 16-lane row
            dxs += __shfl_xor(dxs, off, 64);
            nrm += __shfl_xor(nrm, off, 64);
        }
        const float invn = 1.0f / (sqrtf(nrm) + 1e-16f);

        // F decay + gamma*x (h-independent)
#pragma unroll
        for (int k = 0; k < 8; ++k) {
            F4[k].x = L4[k].x * (F4[k].x * invn); F4[k].y = L4[k].y * (F4[k].y * invn);
            F4[k].z = L4[k].z * (F4[k].z * invn); F4[k].w = L4[k].w * (F4[k].w * invn);
        }
        T0.x *= G4[0].x; T0.y *= G4[0].y; T0.z *= G4[0].z; T0.w *= G4[0].w;
        T1.x *= G4[1].x; T1.y *= G4[1].y; T1.z *= G4[1].z; T1.w *= G4[1].w;
        T2.x *= G4[2].x; T2.y *= G4[2].y; T2.z *= G4[2].z; T2.w *= G4[2].w;
        T3.x *= G4[3].x; T3.y *= G4[3].y; T3.z *= G4[3].z; T3.w *= G4[3].w;

        // ---- gather check (gatherer wave): usually passes first try ----
        if (wv == 0) {
            const unsigned us = (unsigned)s;
            bool ok = ((unsigned)(sa >> 32) >= us) & ((unsigned)(sb >> 32) >= us) &
                      ((unsigned)(sc >> 32) >= us) & ((unsigned)(sd >> 32) >= us);
            while (!__all(ok)) {
                sa = slot_ld(gp);
                sb = slot_ld(gp + 1);
                sc = slot_ld(gp + 2);
                sd = slot_ld(gp + 3);
                ok = ((unsigned)(sa >> 32) >= us) & ((unsigned)(sb >> 32) >= us) &
                     ((unsigned)(sc >> 32) >= us) & ((unsigned)(sd >> 32) >= us);
            }
            float4 hv;
            hv.x = __uint_as_float((unsigned)sa);
            hv.y = __uint_as_float((unsigned)sb);
            hv.z = __uint_as_float((unsigned)sc);
            hv.w = __uint_as_float((unsigned)sd);
            *reinterpret_cast<float4*>(lh[par] + 4 * lane) = hv;
            if (lane == 0)  // release drains the wave's ds_write before the flag
                __hip_atomic_store(&lflag[par], s + 1, __ATOMIC_RELEASE, __HIP_MEMORY_SCOPE_WORKGROUP);
        }

        // ---- Phase W: LDS flag spin, consume h ----
        while (__hip_atomic_load(&lflag[par], __ATOMIC_ACQUIRE, __HIP_MEMORY_SCOPE_WORKGROUP) <= s) {}
        const float4* lh4 = reinterpret_cast<const float4*>(lh[par]);
        float4 H0 = lh4[i], H1 = lh4[16 + i], H2 = lh4[32 + i], H3 = lh4[48 + i];

        // dot_h: 4 independent component chains + tree combine
        float4 a4;
        a4.x = H0.x * tw[0].x; a4.y = H0.y * tw[0].y; a4.z = H0.z * tw[0].z; a4.w = H0.w * tw[0].w;
        a4.x = fmaf(H1.x, tw[1].x, a4.x); a4.y = fmaf(H1.y, tw[1].y, a4.y);
        a4.z = fmaf(H1.z, tw[1].z, a4.z); a4.w = fmaf(H1.w, tw[1].w, a4.w);
        a4.x = fmaf(H2.x, tw[2].x, a4.x); a4.y = fmaf(H2.y, tw[2].y, a4.y);
        a4.z = fmaf(H2.z, tw[2].z, a4.z); a4.w = fmaf(H2.w, tw[2].w, a4.w);
        a4.x = fmaf(H3.x, tw[3].x, a4.x); a4.y = fmaf(H3.y, tw[3].y, a4.y);
        a4.z = fmaf(H3.z, tw[3].z, a4.z); a4.w = fmaf(H3.w, tw[3].w, a4.w);
        float dh = (a4.x + a4.y) + (a4.z + a4.w);
#pragma unroll
        for (int off = 1; off <= 8; off <<= 1) dh += __shfl_xor(dh, off, 64);

        const float e = __expf(2.0f * (dxs + dh + bj));
        const float h = (1.0f - 2.0f / (e + 1.0f)) * invn;
        hl = h;

        // publish ASAP (relaxed agent store, no fence)
        if (i == 0) {
            __hip_atomic_store(slots + ((size_t)(par ^ 1) * BB + b) * HH + r,
                               ((u64)(unsigned)(s + 1) << 32) | (unsigned)__float_as_uint(h),
                               __ATOMIC_RELAXED, __HIP_MEMORY_SCOPE_AGENT);
        }

        // ---- Phase U: F += (gamma*t)*h ----
        F4[0].x = fmaf(T0.x, h, F4[0].x); F4[0].y = fmaf(T0.y, h, F4[0].y);
        F4[0].z = fmaf(T0.z, h, F4[0].z); F4[0].w = fmaf(T0.w, h, F4[0].w);
        F4[1].x = fmaf(T1.x, h, F4[1].x); F4[1].y = fmaf(T1.y, h, F4[1].y);
        F4[1].z = fmaf(T1.z, h, F4[1].z); F4[1].w = fmaf(T1.w, h, F4[1].w);
        F4[2].x = fmaf(T2.x, h, F4[2].x); F4[2].y = fmaf(T2.y, h, F4[2].y);
        F4[2].z = fmaf(T2.z, h, F4[2].z); F4[2].w = fmaf(T2.w, h, F4[2].w);
        F4[3].x = fmaf(T3.x, h, F4[3].x); F4[3].y = fmaf(T3.y, h, F4[3].y);
        F4[3].z = fmaf(T3.z, h, F4[3].z); F4[3].w = fmaf(T3.w, h, F4[3].w);
        F4[4].x = fmaf(G4[4].x * H0.x, h, F4[4].x); F4[4].y = fmaf(G4[4].y * H0.y, h, F4[4].y);
        F4[4].z = fmaf(G4[4].z * H0.z, h, F4[4].z); F4[4].w = fmaf(G4[4].w * H0.w, h, F4[4].w);
        F4[5].x = fmaf(G4[5].x * H1.x, h, F4[5].x); F4[5].y = fmaf(G4[5].y * H1.y, h, F4[5].y);
        F4[5].z = fmaf(G4[5].z * H1.z, h, F4[5].z); F4[5].w = fmaf(G4[5].w * H1.w, h, F4[5].w);
        F4[6].x = fmaf(G4[6].x * H2.x, h, F4[6].x); F4[6].y = fmaf(G4[6].y * H2.y, h, F4[6].y);
        F4[6].z = fmaf(G4[6].z * H2.z, h, F4[6].z); F4[6].w = fmaf(G4[6].w * H2.w, h, F4[6].w);
        F4[7].x = fmaf(G4[7].x * H3.x, h, F4[7].x); F4[7].y = fmaf(G4[7].y * H3.y, h, F4[7].y);
        F4[7].z = fmaf(G4[7].z * H3.z, h, F4[7].z); F4[7].w = fmaf(G4[7].w * H3.w, h, F4[7].w);
    }

    // ---- epilogue: F_T, h_T ----
    {
        float4* fo = reinterpret_cast<float4*>(out + 12288 + ((size_t)b * HH + r) * FWID);
#pragma unroll
        for (int k = 0; k < 8; ++k) fo[k * 16 + i] = F4[k];
    }
    if (i == 0) out[4096 + (size_t)b * HH + r] = hl;

    // tag_space: sl==0 blocks (one per batch) gather final h (stamp TT, parity 0)
    if (sl == 0) {
        if (wv == 0) {
            gather_to_lds(slots + ((size_t)(TT & 1) * BB + b) * HH, lane,
                          (unsigned)TT, lh[0], &lflag[0], TT + 1);
        }
        while (__hip_atomic_load(&lflag[0], __ATOMIC_ACQUIRE, __HIP_MEMORY_SCOPE_WORKGROUP) <= TT) {}
        if (tid < OO) {
            const float* hv = lh[0];
            float acc = bout[tid];
            const float* wo = wout + (size_t)tid * HH;
#pragma unroll 4
            for (int jj = 0; jj < HH; ++jj) acc = fmaf(wo[jj], hv[jj], acc);
            out[(size_t)b * OO + tid] = acc;
        }
    }
}

extern "C" void kernel_launch(void* const* d_in, const int* in_sizes, int n_in,
                              void* d_out, int out_size, void* d_ws, size_t ws_size,
                              hipStream_t stream) {
    (void)in_sizes; (void)n_in; (void)out_size; (void)ws_size;
    const float* x    = (const float*)d_in[0];
    const float* wlam = (const float*)d_in[1];
    const float* wgam = (const float*)d_in[2];
    const float* w    = (const float*)d_in[3];
    const float* bias = (const float*)d_in[4];
    const float* wout = (const float*)d_in[5];
    const float* bout = (const float*)d_in[6];
    float* out = (float*)d_out;

    u64* slots = (u64*)d_ws;

    // stamp 0 + h = 0.0 is exactly what step 0 consumes
    hipMemsetAsync(d_ws, 0, 2ull * BB * HH * 8ull, stream);

    void* args[] = {(void*)&x, (void*)&wlam, (void*)&wgam, (void*)&w, (void*)&bias,
                    (void*)&wout, (void*)&bout, (void*)&out, (void*)&slots};
    hipLaunchCooperativeKernel((void*)stpn_kernel, dim3(256), dim3(512), args, 0, stream);
}